// Round 4
// baseline (473.002 us; speedup 1.0000x reference)
//
#include <hip/hip_runtime.h>

#define SCALE_F 0.08838834764831845f
#define NEG_INF -1e30f

constexpr int S    = 32;
constexpr int Hq   = 32;
constexpr int Hkv  = 8;
constexpr int G    = 4;     // Hq / Hkv
constexpr int D    = 128;
constexpr int BS   = 16;    // kv positions per cache block
constexpr int BMAX = 128;   // max cache blocks per seq
constexpr int KMAX = BMAX * BS;  // 2048

// ---------------------------------------------------------------------------
// Kernel 1: per (s, kv-head, part) partial attention, PARTS compile-time.
// 256 threads. Pass 1: ALL K-block loads issued up front (deep MLP), dot +
// 16-lane shuffle reduce -> scores in LDS. V loads hoisted ABOVE the softmax
// barrier so their latency hides under softmax. Pass 2 consumes V from regs.
// ---------------------------------------------------------------------------
template<int PARTS>
__global__ __launch_bounds__(256, 3)
void attn_part_kernel(const float* __restrict__ q_ptr,
                      const float* __restrict__ kc,
                      const float* __restrict__ vc,
                      const int*   __restrict__ bt,
                      const int*   __restrict__ slens,
                      const float* __restrict__ slopes,
                      float* __restrict__ part_acc,
                      float* __restrict__ part_m,
                      float* __restrict__ part_l)
{
    constexpr int CHUNK = KMAX / PARTS;   // kv positions per part
    constexpr int CPB   = CHUNK / BS;     // kv blocks per part
    constexpr int KT    = (CPB < 8) ? CPB : 8;   // K blocks batched in regs
    constexpr int RPT   = CPB / 2;               // V rows per thread-half
    constexpr int VT    = (RPT < 4) ? RPT : 4;   // V rows batched in regs

    __shared__ __align__(16) float sm_s[G * CHUNK];   // scores, then p
    __shared__ __align__(16) float sm_acc[G * D];     // half-combine buffer

    const int bid  = blockIdx.x;
    const int part = bid % PARTS;
    const int sh   = bid / PARTS;         // s*Hkv + h
    const int h    = sh % Hkv;
    const int s    = sh / Hkv;

    const int seq_len   = slens[s];
    const int num_parts = (seq_len + CHUNK - 1) / CHUNK;
    if (part >= num_parts) return;

    const int tid       = threadIdx.x;
    const int kvb0      = part * CPB;
    const int nb_total  = (seq_len + BS - 1) / BS;
    const int cpb_valid = min(CPB, nb_total - kvb0);  // >= 1 here
    const int lim       = cpb_valid * BS;             // positions with written scores

    float slope[G];
    #pragma unroll
    for (int g = 0; g < G; ++g) slope[g] = slopes[h * G + g];
    const float ctx = (float)(seq_len - 1);

    // Block-table entries: uniform -> SGPRs, all issued up front.
    int phys[CPB];
    #pragma unroll
    for (int i = 0; i < CPB; ++i) phys[i] = bt[s * BMAX + kvb0 + i];

    // ---------------- Pass 1: scores (batched K loads) ----------------
    const int o = tid >> 4;   // position within kv block (0..15)
    const int t = tid & 15;   // d-chunk index: d = t*8 .. t*8+7

    float4 qa[G], qb[G];
    #pragma unroll
    for (int g = 0; g < G; ++g) {
        const float* qp = q_ptr + ((size_t)(s * Hq + h * G + g) * D + t * 8);
        qa[g] = ((const float4*)qp)[0];
        qb[g] = ((const float4*)qp)[1];
    }

    #pragma unroll 1
    for (int base = 0; base < CPB; base += KT) {
        if (base >= cpb_valid) break;
        // Issue ALL KT block loads before any consumption: 2*KT dwordx4 in flight.
        float4 kA[KT], kB[KT];
        #pragma unroll
        for (int j = 0; j < KT; ++j) {
            const int i = base + j;
            if (i < cpb_valid) {
                const float* kp = kc + ((((size_t)phys[i] * Hkv + h) * (D / 8) + t) * BS + o) * 8;
                kA[j] = ((const float4*)kp)[0];
                kB[j] = ((const float4*)kp)[1];
            }
        }
        #pragma unroll
        for (int j = 0; j < KT; ++j) {
            const int i = base + j;
            if (i < cpb_valid) {
                float sc[G];
                #pragma unroll
                for (int g = 0; g < G; ++g)
                    sc[g] = qa[g].x * kA[j].x + qa[g].y * kA[j].y + qa[g].z * kA[j].z + qa[g].w * kA[j].w
                          + qb[g].x * kB[j].x + qb[g].y * kB[j].y + qb[g].z * kB[j].z + qb[g].w * kB[j].w;
                #pragma unroll
                for (int g = 0; g < G; ++g) {
                    #pragma unroll
                    for (int msk = 8; msk >= 1; msk >>= 1)
                        sc[g] += __shfl_xor(sc[g], msk, 16);
                }
                const int kpos   = (kvb0 + i) * BS + o;
                const bool valid = kpos < seq_len;
                if (t == 0) {
                    #pragma unroll
                    for (int g = 0; g < G; ++g)
                        sm_s[g * CHUNK + i * BS + o] =
                            valid ? (SCALE_F * sc[g] + slope[g] * ((float)kpos - ctx)) : NEG_INF;
                }
            }
        }
    }

    // ---------------- V loads hoisted: independent of scores ----------------
    // Issued BEFORE the softmax barrier so HBM latency hides under softmax.
    const int d    = tid & 127;
    const int half = tid >> 7;

    float4 v[VT][4];
    #pragma unroll
    for (int r = 0; r < VT; ++r) {
        const int i = half + 2 * r;
        if (i < cpb_valid) {
            const float4* vp = (const float4*)(vc + (((size_t)phys[i] * Hkv + h) * D + d) * BS);
            v[r][0] = vp[0]; v[r][1] = vp[1]; v[r][2] = vp[2]; v[r][3] = vp[3];
        }
    }

    __syncthreads();

    // ---------------- softmax: wave w handles g = w (bounded by lim) -------
    {
        const int g    = tid >> 6;
        const int lane = tid & 63;
        float m = NEG_INF;
        for (int j = lane; j < lim; j += 64) m = fmaxf(m, sm_s[g * CHUNK + j]);
        #pragma unroll
        for (int msk = 32; msk >= 1; msk >>= 1) m = fmaxf(m, __shfl_xor(m, msk, 64));
        float l = 0.f;
        for (int j = lane; j < lim; j += 64) {
            float p = __expf(sm_s[g * CHUNK + j] - m);
            sm_s[g * CHUNK + j] = p;
            l += p;
        }
        #pragma unroll
        for (int msk = 32; msk >= 1; msk >>= 1) l += __shfl_xor(l, msk, 64);
        if (lane == 0) {
            part_m[(sh * PARTS + part) * G + g] = m;
            part_l[(sh * PARTS + part) * G + g] = l;
        }
    }
    __syncthreads();

    // ---------------- Pass 2: p @ V from registers ----------------
    float acc[G] = {0.f, 0.f, 0.f, 0.f};

    #pragma unroll 1
    for (int t0 = 0; t0 < RPT; t0 += VT) {
        #pragma unroll
        for (int r = 0; r < VT; ++r) {
            const int i = half + 2 * (t0 + r);
            if (i < cpb_valid) {
                #pragma unroll
                for (int g = 0; g < G; ++g) {
                    const float4* pp = (const float4*)(sm_s + g * CHUNK + i * BS);
                    float4 p0 = pp[0], p1 = pp[1], p2 = pp[2], p3 = pp[3];
                    acc[g] += p0.x * v[r][0].x + p0.y * v[r][0].y + p0.z * v[r][0].z + p0.w * v[r][0].w;
                    acc[g] += p1.x * v[r][1].x + p1.y * v[r][1].y + p1.z * v[r][1].z + p1.w * v[r][1].w;
                    acc[g] += p2.x * v[r][2].x + p2.y * v[r][2].y + p2.z * v[r][2].z + p2.w * v[r][2].w;
                    acc[g] += p3.x * v[r][3].x + p3.y * v[r][3].y + p3.z * v[r][3].z + p3.w * v[r][3].w;
                }
            }
        }
        // Fallback path for PARTS < 16: load the next V tile (single tile when PARTS==16).
        if (t0 + VT < RPT) {
            #pragma unroll
            for (int r = 0; r < VT; ++r) {
                const int i = half + 2 * (t0 + VT + r);
                if (i < cpb_valid) {
                    const float4* vp = (const float4*)(vc + (((size_t)phys[i] * Hkv + h) * D + d) * BS);
                    v[r][0] = vp[0]; v[r][1] = vp[1]; v[r][2] = vp[2]; v[r][3] = vp[3];
                }
            }
        }
    }

    if (half == 1) {
        #pragma unroll
        for (int g = 0; g < G; ++g) sm_acc[g * D + d] = acc[g];
    }
    __syncthreads();
    if (half == 0) {
        float* outp = part_acc + (size_t)(sh * PARTS + part) * G * D;
        #pragma unroll
        for (int g = 0; g < G; ++g)
            outp[g * D + d] = acc[g] + sm_acc[g * D + d];
    }
}

// ---------------------------------------------------------------------------
// Kernel 2: combine partials across parts, normalize, write output.
// ---------------------------------------------------------------------------
__global__ __launch_bounds__(512)
void attn_reduce_kernel(const float* __restrict__ part_acc,
                        const float* __restrict__ part_m,
                        const float* __restrict__ part_l,
                        const int*   __restrict__ slens,
                        float* __restrict__ out,
                        int parts, int chunk)
{
    const int sh  = blockIdx.x;      // s*Hkv + h
    const int s   = sh / Hkv;
    const int tid = threadIdx.x;
    const int g   = tid >> 7;
    const int d   = tid & 127;

    const int seq_len = slens[s];
    const int np = min(parts, (seq_len + chunk - 1) / chunk);

    float M = NEG_INF;
    for (int p = 0; p < np; ++p)
        M = fmaxf(M, part_m[(sh * parts + p) * G + g]);
    float L = 0.f, acc = 0.f;
    for (int p = 0; p < np; ++p) {
        const float w = __expf(part_m[(sh * parts + p) * G + g] - M);
        L += w * part_l[(sh * parts + p) * G + g];
        acc += w * part_acc[((size_t)(sh * parts + p) * G + g) * D + d];
    }
    out[(size_t)(sh * G + g) * D + d] = acc / (L + 1e-10f);
}

extern "C" void kernel_launch(void* const* d_in, const int* in_sizes, int n_in,
                              void* d_out, int out_size, void* d_ws, size_t ws_size,
                              hipStream_t stream)
{
    const float* q   = (const float*)d_in[0];
    const float* kc  = (const float*)d_in[1];
    const float* vc  = (const float*)d_in[2];
    const int*   bt  = (const int*)d_in[3];
    const int*   sl  = (const int*)d_in[4];
    const float* slp = (const float*)d_in[5];
    // d_in[6] (query_start_len) is arange(S+1): all rows decode, identity scatter.

    auto ws_need = [](int p) {
        return (size_t)S * Hkv * p * G * (D + 2) * sizeof(float);
    };
    int parts = 16;
    while (parts > 1 && ws_need(parts) > ws_size) parts >>= 1;
    const int chunk = KMAX / parts;

    float* part_acc = (float*)d_ws;
    float* part_m   = part_acc + (size_t)S * Hkv * parts * G * D;
    float* part_l   = part_m   + (size_t)S * Hkv * parts * G;

    const dim3 grid1(S * Hkv * parts);
    switch (parts) {
    case 16: attn_part_kernel<16><<<grid1, 256, 0, stream>>>(q, kc, vc, bt, sl, slp, part_acc, part_m, part_l); break;
    case 8:  attn_part_kernel<8> <<<grid1, 256, 0, stream>>>(q, kc, vc, bt, sl, slp, part_acc, part_m, part_l); break;
    case 4:  attn_part_kernel<4> <<<grid1, 256, 0, stream>>>(q, kc, vc, bt, sl, slp, part_acc, part_m, part_l); break;
    case 2:  attn_part_kernel<2> <<<grid1, 256, 0, stream>>>(q, kc, vc, bt, sl, slp, part_acc, part_m, part_l); break;
    default: attn_part_kernel<1> <<<grid1, 256, 0, stream>>>(q, kc, vc, bt, sl, slp, part_acc, part_m, part_l); break;
    }
    attn_reduce_kernel<<<S * Hkv, 512, 0, stream>>>(
        part_acc, part_m, part_l, sl, (float*)d_out, parts, chunk);
}

// Round 6
// 472.633 us; speedup vs baseline: 1.0008x; 1.0008x over previous
//
#include <hip/hip_runtime.h>

#define SCALE_F 0.08838834764831845f
#define NEG_INF -1e30f

constexpr int S    = 32;
constexpr int Hq   = 32;
constexpr int Hkv  = 8;
constexpr int G    = 4;     // Hq / Hkv
constexpr int D    = 128;
constexpr int BS   = 16;    // kv positions per cache block
constexpr int BMAX = 128;   // max cache blocks per seq
constexpr int KMAX = BMAX * BS;  // 2048

// ---------------------------------------------------------------------------
// Kernel 1: BARRIER-FREE wave-independent partial attention.
// One 64-lane wave owns one (s, kv-head, part) item of CHUNKW kv positions.
// No __syncthreads anywhere: each wave uses a private LDS slice; same-wave
// LDS ordering is handled by compiler lgkmcnt waits, so global loads are
// never drained by barrier semantics (the round-4 finding: s_barrier forces
// s_waitcnt vmcnt(0), which serialized all previous phase overlap).
//
// Per wave:
//   K phase : lanes (o4=lane>>4, t=lane&15); j indexes groups of 4 positions.
//             Batched 8-load K reads, dot, width-16 xor-shuffle reduce over t,
//             lanes t<4 write score[g=t][pos] to private LDS.
//   V pref  : block 0 of V loaded into regs BEFORE softmax (stays in flight —
//             no barrier to drain it).
//   softmax : lanes (g=lane>>4, u=lane&15) reduce over CHUNKW via float4 LDS
//             reads + width-16 shuffles; p written back in place.
//   PV      : double-buffered V register blocks; p read as LDS float4
//             broadcasts; acc[g][2] covers d=lane and d=lane+64.
// ---------------------------------------------------------------------------
template<int PARTS>
__global__ __launch_bounds__(256, 4)
void attn_wave_kernel(const float* __restrict__ q_ptr,
                      const float* __restrict__ kc,
                      const float* __restrict__ vc,
                      const int*   __restrict__ bt,
                      const int*   __restrict__ slens,
                      const float* __restrict__ slopes,
                      float* __restrict__ part_acc,
                      float* __restrict__ part_m,
                      float* __restrict__ part_l)
{
    constexpr int CHUNKW = KMAX / PARTS;   // kv positions per wave item
    constexpr int NCH    = CHUNKW / 64;    // 64-position sub-chunks
    constexpr int CPW    = CHUNKW / BS;    // kv cache blocks per item

    __shared__ float sm_p[4][G * CHUNKW];  // per-wave private score/p buffer

    const int wid  = threadIdx.x >> 6;     // wave within block (0..3)
    const int lane = threadIdx.x & 63;
    const int gw   = blockIdx.x * 4 + wid; // global wave-item id
    const int part = gw % PARTS;
    const int sh   = gw / PARTS;           // s*Hkv + h
    const int h    = sh & (Hkv - 1);
    const int s    = sh >> 3;

    const int seq_len   = slens[s];
    const int num_parts = (seq_len + CHUNKW - 1) / CHUNKW;
    if (part >= num_parts) return;         // divergent exit is safe: no barriers

    float* smp = sm_p[wid];

    // Block-table entries (always in-bounds: entries are valid block ids, so
    // reading K/V beyond seq_len is memory-safe; we mask scores instead).
    int phys[CPW];
    #pragma unroll
    for (int i = 0; i < CPW; ++i) phys[i] = bt[s * BMAX + part * CPW + i];

    const float ctx  = (float)(seq_len - 1);
    const int   pos0 = part * CHUNKW;

    // ---------------- K phase ----------------
    const int o4 = lane >> 4;   // position-within-group (0..3)
    const int t  = lane & 15;   // d-chunk index: d = t*8 .. t*8+7

    const float wslope = slopes[h * G + (t & 3)];  // slope for the g this lane writes

    float4 qa[G], qb[G];
    #pragma unroll
    for (int g = 0; g < G; ++g) {
        const float* qp = q_ptr + ((size_t)(s * Hq + h * G + g) * D + t * 8);
        qa[g] = ((const float4*)qp)[0];
        qb[g] = ((const float4*)qp)[1];
    }

    #pragma unroll
    for (int c = 0; c < NCH; ++c) {
        #pragma unroll
        for (int jb = 0; jb < 4; ++jb) {
            // One kv cache block per batch; 8 float4 loads issued before use.
            const float* kbase = kc + ((((size_t)phys[c * 4 + jb] * Hkv + h) * (D / 8) + t) * BS) * 8;
            float4 kA[4], kB[4];
            #pragma unroll
            for (int j2 = 0; j2 < 4; ++j2) {
                const float* kp = kbase + (j2 * 4 + o4) * 8;
                kA[j2] = ((const float4*)kp)[0];
                kB[j2] = ((const float4*)kp)[1];
            }
            #pragma unroll
            for (int j2 = 0; j2 < 4; ++j2) {
                float sc0 = qa[0].x*kA[j2].x + qa[0].y*kA[j2].y + qa[0].z*kA[j2].z + qa[0].w*kA[j2].w
                          + qb[0].x*kB[j2].x + qb[0].y*kB[j2].y + qb[0].z*kB[j2].z + qb[0].w*kB[j2].w;
                float sc1 = qa[1].x*kA[j2].x + qa[1].y*kA[j2].y + qa[1].z*kA[j2].z + qa[1].w*kA[j2].w
                          + qb[1].x*kB[j2].x + qb[1].y*kB[j2].y + qb[1].z*kB[j2].z + qb[1].w*kB[j2].w;
                float sc2 = qa[2].x*kA[j2].x + qa[2].y*kA[j2].y + qa[2].z*kA[j2].z + qa[2].w*kA[j2].w
                          + qb[2].x*kB[j2].x + qb[2].y*kB[j2].y + qb[2].z*kB[j2].z + qb[2].w*kB[j2].w;
                float sc3 = qa[3].x*kA[j2].x + qa[3].y*kA[j2].y + qa[3].z*kA[j2].z + qa[3].w*kA[j2].w
                          + qb[3].x*kB[j2].x + qb[3].y*kB[j2].y + qb[3].z*kB[j2].z + qb[3].w*kB[j2].w;
                #pragma unroll
                for (int msk = 8; msk >= 1; msk >>= 1) {
                    sc0 += __shfl_xor(sc0, msk, 16);
                    sc1 += __shfl_xor(sc1, msk, 16);
                    sc2 += __shfl_xor(sc2, msk, 16);
                    sc3 += __shfl_xor(sc3, msk, 16);
                }
                if (t < 4) {
                    const int pl   = c * 64 + (jb * 4 + j2) * 4 + o4;  // local pos
                    const int kpos = pos0 + pl;
                    const float scv = (t == 0) ? sc0 : (t == 1) ? sc1 : (t == 2) ? sc2 : sc3;
                    smp[t * CHUNKW + pl] =
                        (kpos < seq_len) ? (SCALE_F * scv + wslope * ((float)kpos - ctx)) : NEG_INF;
                }
            }
        }
    }

    // ---------------- V prefetch (block 0) — stays in flight over softmax ---
    const int d0 = lane;                   // covers d = lane and lane + 64
    float4 vreg[2][2][4];                  // [buf][d-half][pos-quad]
    {
        const float* vb = vc + ((size_t)phys[0] * Hkv + h) * D * BS;
        #pragma unroll
        for (int c = 0; c < 4; ++c) {
            vreg[0][0][c] = ((const float4*)(vb + (size_t)d0 * BS))[c];
            vreg[0][1][c] = ((const float4*)(vb + (size_t)(d0 + 64) * BS))[c];
        }
    }

    // ---------------- softmax (LDS + width-16 shuffles, no barrier) --------
    {
        const int gS = lane >> 4;          // g this lane-group reduces
        const int u  = lane & 15;
        float* rowp = smp + gS * CHUNKW;

        float4 sv[NCH];
        float m = NEG_INF;
        #pragma unroll
        for (int w = 0; w < NCH; ++w) {
            sv[w] = ((const float4*)(rowp + u * 4 + w * 64))[0];
            m = fmaxf(m, fmaxf(fmaxf(sv[w].x, sv[w].y), fmaxf(sv[w].z, sv[w].w)));
        }
        #pragma unroll
        for (int msk = 8; msk >= 1; msk >>= 1) m = fmaxf(m, __shfl_xor(m, msk, 16));

        float l = 0.f;
        #pragma unroll
        for (int w = 0; w < NCH; ++w) {
            float4 pv;
            pv.x = __expf(sv[w].x - m);
            pv.y = __expf(sv[w].y - m);
            pv.z = __expf(sv[w].z - m);
            pv.w = __expf(sv[w].w - m);
            l += pv.x + pv.y + pv.z + pv.w;
            ((float4*)(rowp + u * 4 + w * 64))[0] = pv;
        }
        #pragma unroll
        for (int msk = 8; msk >= 1; msk >>= 1) l += __shfl_xor(l, msk, 16);

        if (u == 0) {
            part_m[(sh * PARTS + part) * G + gS] = m;
            part_l[(sh * PARTS + part) * G + gS] = l;
        }
    }

    // ---------------- PV: double-buffered V regs, p via LDS broadcast ------
    float acc0[G] = {0.f, 0.f, 0.f, 0.f};  // d = lane
    float acc1[G] = {0.f, 0.f, 0.f, 0.f};  // d = lane + 64

    #pragma unroll
    for (int i = 0; i < CPW; ++i) {
        const int cb = i & 1;
        if (i + 1 < CPW) {
            const float* vb = vc + ((size_t)phys[i + 1] * Hkv + h) * D * BS;
            #pragma unroll
            for (int c = 0; c < 4; ++c) {
                vreg[cb ^ 1][0][c] = ((const float4*)(vb + (size_t)d0 * BS))[c];
                vreg[cb ^ 1][1][c] = ((const float4*)(vb + (size_t)(d0 + 64) * BS))[c];
            }
        }
        #pragma unroll
        for (int g = 0; g < G; ++g) {
            const float4* pp = (const float4*)(smp + g * CHUNKW + i * BS);
            #pragma unroll
            for (int c = 0; c < 4; ++c) {
                const float4 p4 = pp[c];   // uniform address: LDS broadcast
                acc0[g] += p4.x * vreg[cb][0][c].x + p4.y * vreg[cb][0][c].y
                         + p4.z * vreg[cb][0][c].z + p4.w * vreg[cb][0][c].w;
                acc1[g] += p4.x * vreg[cb][1][c].x + p4.y * vreg[cb][1][c].y
                         + p4.z * vreg[cb][1][c].z + p4.w * vreg[cb][1][c].w;
            }
        }
    }

    float* outp = part_acc + (size_t)(sh * PARTS + part) * G * D;
    #pragma unroll
    for (int g = 0; g < G; ++g) {
        outp[g * D + d0]      = acc0[g];
        outp[g * D + d0 + 64] = acc1[g];
    }
}

// ---------------------------------------------------------------------------
// Kernel 2: combine partials across parts, normalize, write output.
// ---------------------------------------------------------------------------
__global__ __launch_bounds__(512)
void attn_reduce_kernel(const float* __restrict__ part_acc,
                        const float* __restrict__ part_m,
                        const float* __restrict__ part_l,
                        const int*   __restrict__ slens,
                        float* __restrict__ out,
                        int parts, int chunk)
{
    const int sh  = blockIdx.x;      // s*Hkv + h
    const int s   = sh / Hkv;
    const int tid = threadIdx.x;
    const int g   = tid >> 7;
    const int d   = tid & 127;

    const int seq_len = slens[s];
    const int np = min(parts, (seq_len + chunk - 1) / chunk);

    float M = NEG_INF;
    for (int p = 0; p < np; ++p)
        M = fmaxf(M, part_m[(sh * parts + p) * G + g]);
    float L = 0.f, acc = 0.f;
    for (int p = 0; p < np; ++p) {
        const float w = __expf(part_m[(sh * parts + p) * G + g] - M);
        L += w * part_l[(sh * parts + p) * G + g];
        acc += w * part_acc[((size_t)(sh * parts + p) * G + g) * D + d];
    }
    out[(size_t)(sh * G + g) * D + d] = acc / (L + 1e-10f);
}

extern "C" void kernel_launch(void* const* d_in, const int* in_sizes, int n_in,
                              void* d_out, int out_size, void* d_ws, size_t ws_size,
                              hipStream_t stream)
{
    const float* q   = (const float*)d_in[0];
    const float* kc  = (const float*)d_in[1];
    const float* vc  = (const float*)d_in[2];
    const int*   bt  = (const int*)d_in[3];
    const int*   sl  = (const int*)d_in[4];
    const float* slp = (const float*)d_in[5];
    // d_in[6] (query_start_len) is arange(S+1): all rows decode, identity scatter.

    auto ws_need = [](int p) {
        return (size_t)S * Hkv * p * G * (D + 2) * sizeof(float);
    };
    int parts = 16;
    while (parts > 4 && ws_need(parts) > ws_size) parts >>= 1;
    const int chunk = KMAX / parts;

    float* part_acc = (float*)d_ws;
    float* part_m   = part_acc + (size_t)S * Hkv * parts * G * D;
    float* part_l   = part_m   + (size_t)S * Hkv * parts * G;

    const dim3 grid1(S * Hkv * parts / 4);   // 4 wave-items per 256-thread block
    switch (parts) {
    case 16: attn_wave_kernel<16><<<grid1, 256, 0, stream>>>(q, kc, vc, bt, sl, slp, part_acc, part_m, part_l); break;
    case 8:  attn_wave_kernel<8> <<<grid1, 256, 0, stream>>>(q, kc, vc, bt, sl, slp, part_acc, part_m, part_l); break;
    default: attn_wave_kernel<4> <<<grid1, 256, 0, stream>>>(q, kc, vc, bt, sl, slp, part_acc, part_m, part_l); break;
    }
    attn_reduce_kernel<<<S * Hkv, 512, 0, stream>>>(
        part_acc, part_m, part_l, sl, (float*)d_out, parts, chunk);
}